// Round 1
// baseline (418.238 us; speedup 1.0000x reference)
//
#include <hip/hip_runtime.h>
#include <hip/hip_bf16.h>
#include <stdint.h>

#define NUM_HEADS 6
#define HEAD_DIM  64
#define EMB       384
#define SEQ       2048
#define NBATCH    8
#define NBH       48        // B*H
#define QKV_COLS  1152
#define ROWS      16384     // B*SEQ
#define ATT_SCALE 0.125f
#define L2E       1.44269504f

typedef __attribute__((ext_vector_type(8))) short bf16x8;
typedef __attribute__((ext_vector_type(4))) short bf16x4;
typedef __attribute__((ext_vector_type(4))) float f32x4;

static __device__ __forceinline__ short f2bf(float f) {
    union { float f; uint32_t u; } v; v.f = f;
    uint32_t u = v.u;
    return (short)((u + 0x7FFFu + ((u >> 16) & 1u)) >> 16);   // RNE
}

// ---------- weight transpose + f32->bf16:  in[rows][cols] f32 -> out[cols][rows] bf16
__global__ void wtrans_kernel(const float* __restrict__ in, short* __restrict__ out,
                              int rows, int cols) {
    __shared__ float tile[32][33];
    int c0 = blockIdx.x * 32, r0 = blockIdx.y * 32;
    int x = threadIdx.x, y = threadIdx.y;      // 32 x 8
#pragma unroll
    for (int i = 0; i < 32; i += 8)
        tile[y + i][x] = in[(size_t)(r0 + y + i) * cols + c0 + x];
    __syncthreads();
#pragma unroll
    for (int i = 0; i < 32; i += 8)
        out[(size_t)(c0 + y + i) * rows + r0 + x] = f2bf(tile[x][y + i]);
}

// ---------- QKV GEMM: X[16384][384] f32 @ WT[1152][384] bf16 -> Q,K [B,H,N,D], V^T [B,H,D,N] (bf16)
#define BM 128
#define BN 128
#define BK 64
#define LDP 80   // padded LDS row stride (elements): 160 B, 16B-aligned rows

__global__ __launch_bounds__(256, 2) void qkv_gemm_kernel(
    const float* __restrict__ X, const short* __restrict__ WT,
    const float* __restrict__ bias,
    short* __restrict__ Qb, short* __restrict__ Kb, short* __restrict__ Vt)
{
    __shared__ short At[BM][LDP];
    __shared__ short Bt[BN][LDP];
    const int m0 = blockIdx.x * BM;
    const int n0 = blockIdx.y * BN;
    const int tid = threadIdx.x;
    const int lane = tid & 63, wid = tid >> 6;
    const int wm = wid >> 1, wn = wid & 1;
    const int lr = lane & 15, lg = lane >> 4;
    f32x4 acc[4][4] = {};

    for (int k0 = 0; k0 < EMB; k0 += BK) {
        {   // stage A (f32 -> bf16): 128 rows x 64 cols
            int r = tid >> 4, c = (tid & 15) * 4;
#pragma unroll
            for (int i = 0; i < 8; ++i) {
                f32x4 v = *(const f32x4*)&X[(size_t)(m0 + r + i * 16) * EMB + k0 + c];
                bf16x4 o;
                o[0] = f2bf(v[0]); o[1] = f2bf(v[1]); o[2] = f2bf(v[2]); o[3] = f2bf(v[3]);
                *(bf16x4*)&At[r + i * 16][c] = o;
            }
        }
        {   // stage B (bf16): 128 rows (out-cols) x 64 k
            int r = tid >> 3, c = (tid & 7) * 8;
#pragma unroll
            for (int i = 0; i < 4; ++i) {
                bf16x8 v = *(const bf16x8*)&WT[(size_t)(n0 + r + i * 32) * EMB + k0 + c];
                *(bf16x8*)&Bt[r + i * 32][c] = v;
            }
        }
        __syncthreads();
#pragma unroll
        for (int kk = 0; kk < 2; ++kk) {
            bf16x8 af[4], bg[4];
#pragma unroll
            for (int mi = 0; mi < 4; ++mi)
                af[mi] = *(const bf16x8*)&At[wm * 64 + mi * 16 + lr][kk * 32 + lg * 8];
#pragma unroll
            for (int ni = 0; ni < 4; ++ni)
                bg[ni] = *(const bf16x8*)&Bt[wn * 64 + ni * 16 + lr][kk * 32 + lg * 8];
#pragma unroll
            for (int mi = 0; mi < 4; ++mi)
#pragma unroll
                for (int ni = 0; ni < 4; ++ni)
                    acc[mi][ni] = __builtin_amdgcn_mfma_f32_16x16x32_bf16(af[mi], bg[ni], acc[mi][ni], 0, 0, 0);
        }
        __syncthreads();
    }
    // epilogue: bias + scatter into Q / K / V^T (mat uniform per block: 384 = 3*128)
    const int mat = n0 / EMB;
#pragma unroll
    for (int ni = 0; ni < 4; ++ni) {
        int col = n0 + wn * 64 + ni * 16 + lr;
        float bv = bias[col];
        int rem = col - mat * EMB;
        int h = rem >> 6, d = rem & 63;
#pragma unroll
        for (int mi = 0; mi < 4; ++mi) {
#pragma unroll
            for (int j = 0; j < 4; ++j) {
                int row = m0 + wm * 64 + mi * 16 + lg * 4 + j;
                int b = row >> 11, n = row & 2047;
                short o = f2bf(acc[mi][ni][j] + bv);
                size_t bh = (size_t)(b * NUM_HEADS + h);
                if (mat == 0)      Qb[(bh * SEQ + n) * HEAD_DIM + d] = o;
                else if (mat == 1) Kb[(bh * SEQ + n) * HEAD_DIM + d] = o;
                else               Vt[(bh * HEAD_DIM + d) * SEQ + n] = o;
            }
        }
    }
}

// ---------- flash attention: per block: one (b,h), 64 q rows; 4 waves x 16 q rows each
__global__ __launch_bounds__(256, 2) void attn_kernel(
    const short* __restrict__ Qb, const short* __restrict__ Kb,
    const short* __restrict__ Vt, short* __restrict__ AO)
{
    __shared__ short Pl[4][16][72];   // per-wave P tile [16 q][64 k], 144B row stride
    const int bh = blockIdx.x >> 5;   // 48 heads
    const int qb = blockIdx.x & 31;   // 32 q-blocks of 64
    const int tid = threadIdx.x, lane = tid & 63, wid = tid >> 6;
    const int lr = lane & 15, lg = lane >> 4;
    const int q0 = qb * 64 + wid * 16;
    const short* Qh = Qb + (size_t)bh * SEQ * HEAD_DIM;
    const short* Kh = Kb + (size_t)bh * SEQ * HEAD_DIM;
    const short* Vh = Vt + (size_t)bh * HEAD_DIM * SEQ;

    bf16x8 qf[2];
#pragma unroll
    for (int kk = 0; kk < 2; ++kk)
        qf[kk] = *(const bf16x8*)&Qh[(size_t)(q0 + lr) * HEAD_DIM + kk * 32 + lg * 8];

    f32x4 acc[4] = {};
    float mrun[4] = { -1e30f, -1e30f, -1e30f, -1e30f };
    float lsum[4] = { 0.f, 0.f, 0.f, 0.f };

    for (int kt = 0; kt < SEQ / 64; ++kt) {
        const int kbase = kt * 64;
        f32x4 s[4] = {};
#pragma unroll
        for (int c = 0; c < 4; ++c)
#pragma unroll
            for (int kk = 0; kk < 2; ++kk) {
                bf16x8 kf = *(const bf16x8*)&Kh[(size_t)(kbase + c * 16 + lr) * HEAD_DIM + kk * 32 + lg * 8];
                s[c] = __builtin_amdgcn_mfma_f32_16x16x32_bf16(qf[kk], kf, s[c], 0, 0, 0);
            }
        // online softmax; row = lg*4+j lives in the 16 lanes of group lg -> xor masks 1,2,4,8
        float p[4][4];
#pragma unroll
        for (int j = 0; j < 4; ++j) {
            float mx = fmaxf(fmaxf(s[0][j], s[1][j]), fmaxf(s[2][j], s[3][j])) * ATT_SCALE;
#pragma unroll
            for (int msk = 1; msk < 16; msk <<= 1)
                mx = fmaxf(mx, __shfl_xor(mx, msk, 64));
            float mnew = fmaxf(mrun[j], mx);
            float r = __builtin_amdgcn_exp2f((mrun[j] - mnew) * L2E);
            float ps = 0.f;
#pragma unroll
            for (int c = 0; c < 4; ++c) {
                float pv = __builtin_amdgcn_exp2f((s[c][j] * ATT_SCALE - mnew) * L2E);
                p[c][j] = pv; ps += pv;
            }
#pragma unroll
            for (int msk = 1; msk < 16; msk <<= 1)
                ps += __shfl_xor(ps, msk, 64);
            lsum[j] = lsum[j] * r + ps;
            mrun[j] = mnew;
#pragma unroll
            for (int f = 0; f < 4; ++f) acc[f][j] *= r;
        }
        // P: C-layout -> LDS -> A-layout
#pragma unroll
        for (int c = 0; c < 4; ++c)
#pragma unroll
            for (int j = 0; j < 4; ++j)
                Pl[wid][lg * 4 + j][c * 16 + lr] = f2bf(p[c][j]);
        asm volatile("s_waitcnt lgkmcnt(0)" ::: "memory");
        bf16x8 pa[2];
#pragma unroll
        for (int kk = 0; kk < 2; ++kk)
            pa[kk] = *(const bf16x8*)&Pl[wid][lr][kk * 32 + lg * 8];
#pragma unroll
        for (int f = 0; f < 4; ++f)
#pragma unroll
            for (int kk = 0; kk < 2; ++kk) {
                bf16x8 vb = *(const bf16x8*)&Vh[(size_t)(f * 16 + lr) * SEQ + kbase + kk * 32 + lg * 8];
                acc[f] = __builtin_amdgcn_mfma_f32_16x16x32_bf16(pa[kk], vb, acc[f], 0, 0, 0);
            }
        asm volatile("s_waitcnt lgkmcnt(0)" ::: "memory");  // reads drained before next tile's writes
    }
    // epilogue -> AO [B,N,C] bf16 (c = h*64 + d)
    const int b = bh / NUM_HEADS, h = bh - b * NUM_HEADS;
#pragma unroll
    for (int f = 0; f < 4; ++f)
#pragma unroll
        for (int j = 0; j < 4; ++j) {
            int row = q0 + lg * 4 + j;
            float v = acc[f][j] / lsum[j];
            AO[((size_t)(b * SEQ + row)) * EMB + h * HEAD_DIM + f * 16 + lr] = f2bf(v);
        }
}

// ---------- proj GEMM: AO[16384][384] bf16 @ WT[384][384] bf16 + bias -> f32 out
__global__ __launch_bounds__(256, 2) void proj_gemm_kernel(
    const short* __restrict__ Ain, const short* __restrict__ WT,
    const float* __restrict__ bias, float* __restrict__ Out)
{
    __shared__ short At[BM][LDP];
    __shared__ short Bt[BN][LDP];
    const int m0 = blockIdx.x * BM;
    const int n0 = blockIdx.y * BN;
    const int tid = threadIdx.x;
    const int lane = tid & 63, wid = tid >> 6;
    const int wm = wid >> 1, wn = wid & 1;
    const int lr = lane & 15, lg = lane >> 4;
    f32x4 acc[4][4] = {};

    for (int k0 = 0; k0 < EMB; k0 += BK) {
        {
            int r = tid >> 3, c = (tid & 7) * 8;
#pragma unroll
            for (int i = 0; i < 4; ++i) {
                bf16x8 v = *(const bf16x8*)&Ain[(size_t)(m0 + r + i * 32) * EMB + k0 + c];
                *(bf16x8*)&At[r + i * 32][c] = v;
            }
#pragma unroll
            for (int i = 0; i < 4; ++i) {
                bf16x8 v = *(const bf16x8*)&WT[(size_t)(n0 + r + i * 32) * EMB + k0 + c];
                *(bf16x8*)&Bt[r + i * 32][c] = v;
            }
        }
        __syncthreads();
#pragma unroll
        for (int kk = 0; kk < 2; ++kk) {
            bf16x8 af[4], bg[4];
#pragma unroll
            for (int mi = 0; mi < 4; ++mi)
                af[mi] = *(const bf16x8*)&At[wm * 64 + mi * 16 + lr][kk * 32 + lg * 8];
#pragma unroll
            for (int ni = 0; ni < 4; ++ni)
                bg[ni] = *(const bf16x8*)&Bt[wn * 64 + ni * 16 + lr][kk * 32 + lg * 8];
#pragma unroll
            for (int mi = 0; mi < 4; ++mi)
#pragma unroll
                for (int ni = 0; ni < 4; ++ni)
                    acc[mi][ni] = __builtin_amdgcn_mfma_f32_16x16x32_bf16(af[mi], bg[ni], acc[mi][ni], 0, 0, 0);
        }
        __syncthreads();
    }
#pragma unroll
    for (int ni = 0; ni < 4; ++ni) {
        int col = n0 + wn * 64 + ni * 16 + lr;
        float bv = bias[col];
#pragma unroll
        for (int mi = 0; mi < 4; ++mi)
#pragma unroll
            for (int j = 0; j < 4; ++j) {
                int row = m0 + wm * 64 + mi * 16 + lg * 4 + j;
                Out[(size_t)row * EMB + col] = acc[mi][ni][j] + bv;
            }
    }
}

extern "C" void kernel_launch(void* const* d_in, const int* in_sizes, int n_in,
                              void* d_out, int out_size, void* d_ws, size_t ws_size,
                              hipStream_t stream) {
    const float* x      = (const float*)d_in[0];
    const float* qkv_w  = (const float*)d_in[1];   // [384][1152]
    const float* qkv_b  = (const float*)d_in[2];   // [1152]
    const float* proj_w = (const float*)d_in[3];   // [384][384]
    const float* proj_b = (const float*)d_in[4];   // [384]
    float* out = (float*)d_out;

    // workspace layout (bytes), total ~51.5 MB
    char* ws = (char*)d_ws;
    short* qkv_wT  = (short*)(ws);               // [1152][384] bf16
    short* proj_wT = (short*)(ws + 884736);      // [384][384]  bf16
    short* Qb      = (short*)(ws + 1179648);     // [B,H,N,D]   bf16
    short* Kb      = (short*)(ws + 13762560);    // [B,H,N,D]   bf16
    short* Vt      = (short*)(ws + 26345472);    // [B,H,D,N]   bf16
    short* AO      = (short*)(ws + 38928384);    // [B,N,C]     bf16

    wtrans_kernel<<<dim3(QKV_COLS / 32, EMB / 32), dim3(32, 8), 0, stream>>>(qkv_w, qkv_wT, EMB, QKV_COLS);
    wtrans_kernel<<<dim3(EMB / 32, EMB / 32), dim3(32, 8), 0, stream>>>(proj_w, proj_wT, EMB, EMB);
    qkv_gemm_kernel<<<dim3(ROWS / BM, QKV_COLS / BN), 256, 0, stream>>>(x, qkv_wT, qkv_b, Qb, Kb, Vt);
    attn_kernel<<<dim3(NBH * (SEQ / 64)), 256, 0, stream>>>(Qb, Kb, Vt, AO);
    proj_gemm_kernel<<<dim3(ROWS / BM, EMB / BN), 256, 0, stream>>>(AO, proj_wT, proj_b, out);
}